// Round 3
// baseline (837.946 us; speedup 1.0000x reference)
//
#include <hip/hip_runtime.h>

// PillarFeatureNet: out = scatter_add(relu(BN(x@W^T + b)), cells), grid 512x512x64.
// BN stats computed analytically from x's 6x6 covariance (bias cancels in var),
// BN+ReLU folded into the linear. Scatter via deterministic two-level counting
// sort (zero global atomics) + per-bucket LDS slab accumulation.

constexpr int NPTS   = 2000000;
constexpr int NBUCK  = 2048;   // coarse buckets = cell >> 7
constexpr int CPB    = 128;    // cells per bucket
constexpr int NBLK   = 256;    // partition blocks
constexpr int CHUNK  = 7813;   // ceil(NPTS / NBLK); 256*7813 >= 2M
constexpr float EPS  = 1e-5f;

// Workspace layout (4-byte elements):
constexpr int WS_WP     = 0;        // 64*6 folded weights
constexpr int WS_BP     = 384;      // 64 folded bias
constexpr int WS_STARTS = 448;      // NBUCK+1 bucket start offsets
constexpr int WS_HIST   = 2560;     // NBLK*NBUCK per-block histograms
constexpr int WS_BASES  = WS_HIST + NBLK * NBUCK;    // NBLK*NBUCK per-block bases
constexpr int WS_BSTATS = WS_BASES + NBLK * NBUCK;   // NBLK*27 partial stats
constexpr int WS_SORTED = WS_BSTATS + NBLK * 32;     // NPTS packed records
// total ~ 12.2 MB

__device__ __forceinline__ float wave_sum64(float v) {
#pragma unroll
    for (int off = 32; off > 0; off >>= 1) v += __shfl_down(v, off, 64);
    return v;
}

// ---- K1: per-block histogram over 2048 buckets (no global atomics) ----
__global__ __launch_bounds__(1024) void hist_kernel(const int2* __restrict__ idx,
                                                    int* __restrict__ hist) {
    __shared__ int lh[NBUCK];
    for (int i = threadIdx.x; i < NBUCK; i += 1024) lh[i] = 0;
    __syncthreads();
    const int beg = blockIdx.x * CHUNK;
    const int end = min(NPTS, beg + CHUNK);
    for (int p = beg + threadIdx.x; p < end; p += 1024) {
        const int2 ij = idx[p];
        atomicAdd(&lh[(ij.x << 2) | (ij.y >> 7)], 1);
    }
    __syncthreads();
    int* out = hist + blockIdx.x * NBUCK;
    for (int i = threadIdx.x; i < NBUCK; i += 1024) out[i] = lh[i];
}

// ---- K2a: column scan over blocks -> per-(block,bucket) bases + totals ----
__global__ __launch_bounds__(64) void colscan_kernel(const int* __restrict__ hist,
                                                     int* __restrict__ bases,
                                                     int* __restrict__ starts) {
    const int b = blockIdx.x * 64 + threadIdx.x;  // bucket id, 2048 threads total
    int run = 0;
    for (int blk = 0; blk < NBLK; ++blk) {
        bases[blk * NBUCK + b] = run;
        run += hist[blk * NBUCK + b];
    }
    starts[b] = run;  // bucket total (scanned in place by K2b)
}

// ---- K2b: exclusive scan of 2048 bucket totals (in place) ----
__global__ __launch_bounds__(1024) void scan_kernel(int* __restrict__ starts) {
    __shared__ int wsum[16];
    const int t = threadIdx.x, lane = t & 63, wv = t >> 6;
    const int v0 = starts[2 * t], v1 = starts[2 * t + 1];
    const int v = v0 + v1;
    int incl = v;
#pragma unroll
    for (int d = 1; d < 64; d <<= 1) {
        int u = __shfl_up(incl, d, 64);
        if (lane >= d) incl += u;
    }
    if (lane == 63) wsum[wv] = incl;
    __syncthreads();
    int pre = 0;
#pragma unroll
    for (int w = 0; w < 16; ++w) {
        int sv = wsum[w];
        if (w < wv) pre += sv;
    }
    const int excl = pre + incl - v;
    starts[2 * t] = excl;
    starts[2 * t + 1] = excl + v0;
    if (t == 1023) starts[NBUCK] = excl + v;  // == NPTS
}

// ---- K3: scatter packed records to exact final slots + x stats (no global atomics) ----
__global__ __launch_bounds__(1024) void scatter_kernel(const float* __restrict__ x,
                                                       const int2* __restrict__ idx,
                                                       const int* __restrict__ starts,
                                                       const int* __restrict__ bases,
                                                       int* __restrict__ sorted,
                                                       float* __restrict__ bstats) {
    __shared__ int lbase[NBUCK];   // 8 KB
    __shared__ int lcur[NBUCK];    // 8 KB
    __shared__ float lstats[16][27];
    const int blk = blockIdx.x;
    for (int i = threadIdx.x; i < NBUCK; i += 1024) {
        lbase[i] = starts[i] + bases[blk * NBUCK + i];
        lcur[i] = 0;
    }
    __syncthreads();

    float acc[27];
#pragma unroll
    for (int i = 0; i < 27; ++i) acc[i] = 0.f;

    const int beg = blk * CHUNK;
    const int end = min(NPTS, beg + CHUNK);
    for (int p = beg + threadIdx.x; p < end; p += 1024) {
        const int2 ij = idx[p];
        const int b = (ij.x << 2) | (ij.y >> 7);
        const int rank = atomicAdd(&lcur[b], 1);           // LDS returning atomic
        sorted[lbase[b] + rank] = (p << 7) | (ij.y & 127); // pid(21b) | cell_local(7b)
        float v[6];
#pragma unroll
        for (int k = 0; k < 6; ++k) v[k] = x[(size_t)p * 6 + k];
        int c = 6;
#pragma unroll
        for (int k = 0; k < 6; ++k) {
            acc[k] += v[k];
#pragma unroll
            for (int l = k; l < 6; ++l) { acc[c] += v[k] * v[l]; ++c; }
        }
    }

    const int lane = threadIdx.x & 63, wv = threadIdx.x >> 6;
#pragma unroll
    for (int i = 0; i < 27; ++i) {
        const float s = wave_sum64(acc[i]);
        if (lane == 0) lstats[wv][i] = s;
    }
    __syncthreads();
    if (threadIdx.x < 27) {
        float s = 0.f;
        for (int w = 0; w < 16; ++w) s += lstats[w][threadIdx.x];
        bstats[blk * 32 + threadIdx.x] = s;
    }
}

// ---- K3b: reduce stats, compute BN fold ----
__global__ __launch_bounds__(64) void bnfold_kernel(const float* __restrict__ bstats,
                                                    const float* __restrict__ W,
                                                    const float* __restrict__ b,
                                                    const float* __restrict__ gamma,
                                                    const float* __restrict__ beta,
                                                    float* __restrict__ ws) {
    __shared__ float s27[27];
    __shared__ float m[6], C[36];
    const int t = threadIdx.x;
    if (t < 27) {
        float s = 0.f;
        for (int blk = 0; blk < NBLK; ++blk) s += bstats[blk * 32 + t];
        s27[t] = s;
    }
    __syncthreads();
    if (t == 0) {
        const float invN = 1.0f / (float)NPTS;
        float mm[6];
        for (int k = 0; k < 6; ++k) { mm[k] = s27[k] * invN; m[k] = mm[k]; }
        int c = 6;
        for (int k = 0; k < 6; ++k)
            for (int l = k; l < 6; ++l) {
                const float cov = s27[c] * invN - mm[k] * mm[l];
                ++c;
                C[k * 6 + l] = cov;
                C[l * 6 + k] = cov;
            }
    }
    __syncthreads();
    float w[6];
#pragma unroll
    for (int k = 0; k < 6; ++k) w[k] = W[t * 6 + k];
    float mh = b[t];
#pragma unroll
    for (int k = 0; k < 6; ++k) mh += w[k] * m[k];
    float var = 0.f;
#pragma unroll
    for (int k = 0; k < 6; ++k)
#pragma unroll
        for (int l = 0; l < 6; ++l) var += w[k] * w[l] * C[k * 6 + l];
    const float s = gamma[t] * rsqrtf(var + EPS);
#pragma unroll
    for (int k = 0; k < 6; ++k) ws[WS_WP + t * 6 + k] = w[k] * s;
    ws[WS_BP + t] = beta[t] + s * (b[t] - mh);
}

// ---- K4: one block per bucket; LDS slab accumulate; single coalesced store ----
__global__ __launch_bounds__(1024) void accum_kernel(const float* __restrict__ x,
                                                     const int* __restrict__ sorted,
                                                     const int* __restrict__ starts,
                                                     const float* __restrict__ wsp,
                                                     float* __restrict__ grid) {
    __shared__ float slab[CPB * 64];  // 32 KB
    const int t = threadIdx.x, lane = t & 63, wv = t >> 6;
    for (int i = t; i < CPB * 64; i += 1024) slab[i] = 0.f;

    const float w0 = wsp[WS_WP + lane * 6 + 0];
    const float w1 = wsp[WS_WP + lane * 6 + 1];
    const float w2 = wsp[WS_WP + lane * 6 + 2];
    const float w3 = wsp[WS_WP + lane * 6 + 3];
    const float w4 = wsp[WS_WP + lane * 6 + 4];
    const float w5 = wsp[WS_WP + lane * 6 + 5];
    const float bb = wsp[WS_BP + lane];

    const int s = starts[blockIdx.x];
    const int e = starts[blockIdx.x + 1];
    __syncthreads();

    for (int base = s + wv * 64; base < e; base += 16 * 64) {
        const int n = min(64, e - base);
        int rec = 0;
        float2 xa = {0.f, 0.f}, xb = {0.f, 0.f}, xc = {0.f, 0.f};
        if (lane < n) {
            rec = sorted[base + lane];
            const float2* xp = (const float2*)(x + (size_t)(rec >> 7) * 6);
            xa = xp[0]; xb = xp[1]; xc = xp[2];
        }
#define PT_BODY(PT)                                                                        \
        {                                                                                  \
            const int r = __builtin_amdgcn_readlane(rec, (PT));                            \
            const float x0 = __uint_as_float(__builtin_amdgcn_readlane(__float_as_uint(xa.x), (PT))); \
            const float x1 = __uint_as_float(__builtin_amdgcn_readlane(__float_as_uint(xa.y), (PT))); \
            const float x2 = __uint_as_float(__builtin_amdgcn_readlane(__float_as_uint(xb.x), (PT))); \
            const float x3 = __uint_as_float(__builtin_amdgcn_readlane(__float_as_uint(xb.y), (PT))); \
            const float x4 = __uint_as_float(__builtin_amdgcn_readlane(__float_as_uint(xc.x), (PT))); \
            const float x5 = __uint_as_float(__builtin_amdgcn_readlane(__float_as_uint(xc.y), (PT))); \
            float h = fmaf(w0, x0, fmaf(w1, x1, fmaf(w2, x2,                               \
                      fmaf(w3, x3, fmaf(w4, x4, fmaf(w5, x5, bb))))));                     \
            h = fmaxf(h, 0.f);                                                             \
            atomicAdd(&slab[(r & 127) * 64 + lane], h);                                    \
        }
        if (n == 64) {
#pragma unroll
            for (int pt = 0; pt < 64; ++pt) PT_BODY(pt)
        } else {
            for (int pt = 0; pt < n; ++pt) PT_BODY(pt)
        }
#undef PT_BODY
    }
    __syncthreads();

    float4* g4 = (float4*)(grid + (size_t)blockIdx.x * CPB * 64);
    const float4* s4 = (const float4*)slab;
    for (int i = t; i < CPB * 16; i += 1024) g4[i] = s4[i];
}

extern "C" void kernel_launch(void* const* d_in, const int* in_sizes, int n_in,
                              void* d_out, int out_size, void* d_ws, size_t ws_size,
                              hipStream_t stream) {
    const float* x       = (const float*)d_in[0];
    const int2*  indices = (const int2*)d_in[1];
    const float* W       = (const float*)d_in[2];
    const float* b       = (const float*)d_in[3];
    const float* gamma   = (const float*)d_in[4];
    const float* beta    = (const float*)d_in[5];
    float* out = (float*)d_out;
    float* wsf = (float*)d_ws;
    int*   wsi = (int*)d_ws;

    int*   hist   = wsi + WS_HIST;
    int*   bases  = wsi + WS_BASES;
    int*   starts = wsi + WS_STARTS;
    int*   sorted = wsi + WS_SORTED;
    float* bstats = wsf + WS_BSTATS;

    hist_kernel<<<NBLK, 1024, 0, stream>>>(indices, hist);
    colscan_kernel<<<NBUCK / 64, 64, 0, stream>>>(hist, bases, starts);
    scan_kernel<<<1, 1024, 0, stream>>>(starts);
    scatter_kernel<<<NBLK, 1024, 0, stream>>>(x, indices, starts, bases, sorted, bstats);
    bnfold_kernel<<<1, 64, 0, stream>>>(bstats, W, b, gamma, beta, wsf);
    accum_kernel<<<NBUCK, 1024, 0, stream>>>(x, sorted, starts, wsf, out);
}